// Round 4
// baseline (36.226 us; speedup 1.0000x reference)
//
#include <hip/hip_runtime.h>

#define NEG_INF_F (-10000.0f)
#define EPS_F (1e-8f)

typedef float f4 __attribute__((ext_vector_type(4)));

// ---------------------------------------------------------------------------
// Kernel A fast path (H known at compile time): 16 lanes per row, 4 rows per
// wave. 8192 waves (full 32-waves/CU TLP), reduction is 4 shuffle levels
// amortized over 4 rows (3 swizzles/row vs 36 in the 1-row/wave version),
// q elements loaded once per 4 rows (broadcasty L1 hits).
// Per VMEM instruction: 4 rows x 256 B contiguous slices = 16 fully-used lines.
// ---------------------------------------------------------------------------
template <int H>
__global__ __launch_bounds__(256) void row_stats_fast4(
    const float* __restrict__ seq, const int* __restrict__ idxs,
    float* __restrict__ d1, float* __restrict__ d2, float* __restrict__ n2,
    int S, int nrows) {
  constexpr int NF4 = H / 4;     // f4 per row
  constexpr int ITERS = H / 64;  // per-lane f4 loads (16 lanes/row)
  int wave = blockIdx.x * 4 + (threadIdx.x >> 6);
  int lane = threadIdx.x & 63;
  int r = lane >> 4;             // row within wave (0..3)
  int k = lane & 15;             // lane within row
  int row = wave * 4 + r;
  if (row >= nrows) return;

  int b = row / S;               // S % 4 == 0 -> all 4 rows in one batch
  int sep0 = idxs[2 * b];

  const f4* rowp = reinterpret_cast<const f4*>(seq) + (size_t)row * NF4 + k;
  const f4* q1p =
      reinterpret_cast<const f4*>(seq) + ((size_t)b * S + 1) * NF4 + k;
  const f4* q2p =
      reinterpret_cast<const f4*>(seq) + ((size_t)b * S + (sep0 - 1)) * NF4 + k;

  float s1 = 0.f, s2 = 0.f, sn = 0.f;
  #pragma unroll 4
  for (int i = 0; i < ITERS; ++i) {
    f4 x = __builtin_nontemporal_load(rowp + i * 16);
    f4 a = q1p[i * 16];
    f4 c = q2p[i * 16];
    s1 += x[0] * a[0] + x[1] * a[1] + x[2] * a[2] + x[3] * a[3];
    s2 += x[0] * c[0] + x[1] * c[1] + x[2] * c[2] + x[3] * c[3];
    sn += x[0] * x[0] + x[1] * x[1] + x[2] * x[2] + x[3] * x[3];
  }

  // Reduce across the 16 lanes of each row-group (4 rows in parallel).
  #pragma unroll
  for (int off = 8; off >= 1; off >>= 1) {
    s1 += __shfl_xor(s1, off, 64);
    s2 += __shfl_xor(s2, off, 64);
    sn += __shfl_xor(sn, off, 64);
  }
  if (k == 0) {
    d1[row] = s1;
    d2[row] = s2;
    n2[row] = sn;
  }
}

// Generic fallback (runtime H): one wave per row.
__global__ __launch_bounds__(256) void row_stats_kernel(
    const float* __restrict__ seq, const int* __restrict__ idxs,
    float* __restrict__ d1, float* __restrict__ d2, float* __restrict__ n2,
    int B, int S, int H) {
  int gtid = blockIdx.x * blockDim.x + threadIdx.x;
  int row = gtid >> 6;
  int lane = threadIdx.x & 63;
  int nrows = B * S;
  if (row >= nrows) return;

  int b = row / S;
  int sep0 = idxs[b * 2 + 0];

  const float* rowp = seq + (size_t)row * H;
  const float* q1p = seq + ((size_t)b * S + 1) * H;
  const float* q2p = seq + ((size_t)b * S + (sep0 - 1)) * H;

  float s1 = 0.f, s2 = 0.f, sn = 0.f;
  for (int h = lane * 4; h < H; h += 64 * 4) {
    float4 x = *reinterpret_cast<const float4*>(rowp + h);
    float4 a = *reinterpret_cast<const float4*>(q1p + h);
    float4 c = *reinterpret_cast<const float4*>(q2p + h);
    s1 += x.x * a.x + x.y * a.y + x.z * a.z + x.w * a.w;
    s2 += x.x * c.x + x.y * c.y + x.z * c.z + x.w * c.w;
    sn += x.x * x.x + x.y * x.y + x.z * x.z + x.w * x.w;
  }
  #pragma unroll
  for (int off = 32; off >= 1; off >>= 1) {
    s1 += __shfl_xor(s1, off, 64);
    s2 += __shfl_xor(s2, off, 64);
    sn += __shfl_xor(sn, off, 64);
  }
  if (lane == 0) {
    d1[row] = s1;
    d2[row] = s2;
    n2[row] = sn;
  }
}

// ---------------------------------------------------------------------------
// Kernel B (L=32 compile-time): one thread per (b,s), full unroll, rsqrt.
// First-occurrence argmax via strict '>' (matches jnp.argmax).
// ---------------------------------------------------------------------------
template <int L>
__global__ __launch_bounds__(64) void window_max_fast(
    const float* __restrict__ d1, const float* __restrict__ d2,
    const float* __restrict__ n2, const int* __restrict__ idxs,
    float* __restrict__ out, int S, int nrows) {
  int t = blockIdx.x * 64 + threadIdx.x;
  if (t >= nrows) return;
  int b = t / S;
  int s = t - b * S;

  int sep0 = idxs[b * 2 + 0];
  int sep1 = idxs[b * 2 + 1];

  size_t bS = (size_t)b * S;
  float qn2 = n2[bS + 1] + n2[bS + (sep0 - 1)];
  float my_d1 = d1[t];
  float my_n2 = n2[t];

  const float* d2b = d2 + bS;
  const float* n2b = n2 + bS;

  float best = NEG_INF_F;
  int best_l = 0;
  #pragma unroll
  for (int l = 0; l < L; ++l) {
    int j = min(s + l, S - 1);
    float w2 = n2b[j];
    float v2 = d2b[j];
    float prod = (my_n2 + w2) * qn2;
    float sim = (my_d1 + v2) * __frsqrt_rn(fmaxf(prod, EPS_F * EPS_F));
    sim = (s + l < sep1) ? sim : NEG_INF_F;
    if (sim > best) { best = sim; best_l = l; }
  }

  bool valid_i = (s > sep0) && (s < sep1);
  out[t] = valid_i ? best : NEG_INF_F;
  out[nrows + t] = valid_i ? (float)(s + best_l) : -1.0f;
}

// Generic fallback (runtime L), precise math.
__global__ __launch_bounds__(256) void window_max_kernel(
    const float* __restrict__ d1, const float* __restrict__ d2,
    const float* __restrict__ n2, const int* __restrict__ idxs,
    const int* __restrict__ pL,
    float* __restrict__ out, int B, int S) {
  int t = blockIdx.x * blockDim.x + threadIdx.x;
  int nrows = B * S;
  if (t >= nrows) return;
  int b = t / S;
  int s = t - b * S;

  int sep0 = idxs[b * 2 + 0];
  int sep1 = idxs[b * 2 + 1];
  int L = pL[0];

  float qn2 = n2[(size_t)b * S + 1] + n2[(size_t)b * S + (sep0 - 1)];
  float my_d1 = d1[t];
  float my_n2 = n2[t];

  float best = NEG_INF_F;
  int best_l = 0;
  const float* d2b = d2 + (size_t)b * S;
  const float* n2b = n2 + (size_t)b * S;
  for (int l = 0; l < L; ++l) {
    float sim;
    if (s + l < sep1) {
      int j = min(s + l, S - 1);
      float denom = fmaxf(sqrtf((my_n2 + n2b[j]) * qn2), EPS_F);
      sim = (my_d1 + d2b[j]) / denom;
    } else {
      sim = NEG_INF_F;
    }
    if (sim > best) { best = sim; best_l = l; }
  }

  bool valid_i = (s > sep0) && (s < sep1);
  out[t] = valid_i ? best : NEG_INF_F;
  out[nrows + t] = valid_i ? (float)(s + best_l) : -1.0f;
}

extern "C" void kernel_launch(void* const* d_in, const int* in_sizes, int n_in,
                              void* d_out, int out_size, void* d_ws, size_t ws_size,
                              hipStream_t stream) {
  const float* seq = (const float*)d_in[0];
  const int* idxs = (const int*)d_in[1];
  const int* pL = (const int*)d_in[2];

  int B = in_sizes[1] / 2;
  int S = out_size / (2 * B);
  int H = (int)((long long)in_sizes[0] / ((long long)B * S));
  int nrows = B * S;

  float* d1 = (float*)d_ws;
  float* d2 = d1 + nrows;
  float* n2 = d2 + nrows;

  if (H == 1024 && (S % 4) == 0) {
    // 4 rows per wave, 4 waves per block -> 16 rows per block.
    int gridA = (nrows + 15) / 16;
    row_stats_fast4<1024><<<gridA, 256, 0, stream>>>(seq, idxs, d1, d2, n2, S,
                                                     nrows);
  } else {
    int gridA = (nrows + 3) / 4;
    row_stats_kernel<<<gridA, 256, 0, stream>>>(seq, idxs, d1, d2, n2, B, S, H);
  }

  int gridB = (nrows + 63) / 64;
  window_max_fast<32><<<gridB, 64, 0, stream>>>(d1, d2, n2, idxs,
                                                (float*)d_out, S, nrows);
  (void)pL;
}

// Round 5
// 31.074 us; speedup vs baseline: 1.1658x; 1.1658x over previous
//
#include <hip/hip_runtime.h>

#define NEG_INF_F (-10000.0f)
#define EPS_F (1e-8f)

typedef float f4 __attribute__((ext_vector_type(4)));

// ---------------------------------------------------------------------------
// Kernel A fast path: one wave per 4 consecutive rows, software-pipelined
// depth 2. Per row the structure is IDENTICAL to the proven r3 kernel
// (4 nt float4 loads, same FMA order, full 6-level butterfly) so results are
// bit-identical; the only change is that row r+1's loads are issued before
// row r's reduce, so the shuffle/store tail always has HBM traffic in flight.
// q1/q2 slices are hoisted once per wave. 8192 waves -> full TLP.
// ---------------------------------------------------------------------------
template <int H>
__global__ __launch_bounds__(256) void row_stats_pipe(
    const float* __restrict__ seq, const int* __restrict__ idxs,
    float* __restrict__ d1, float* __restrict__ d2, float* __restrict__ n2,
    int S, int nrows) {
  constexpr int NF4 = H / 4;   // f4 per row
  constexpr int C = H / 256;   // f4 loads per lane per row (4 for H=1024)
  constexpr int R = 4;         // rows per wave (pipelined)
  int wave = blockIdx.x * 4 + (threadIdx.x >> 6);
  int lane = threadIdx.x & 63;
  int row0 = wave * R;
  if (row0 >= nrows) return;

  int b = row0 / S;            // S % 4 == 0 -> all R rows in one batch
  int sep0 = idxs[2 * b];

  const f4* base = reinterpret_cast<const f4*>(seq);
  const f4* q1p = base + ((size_t)b * S + 1) * NF4 + lane;
  const f4* q2p = base + ((size_t)b * S + (sep0 - 1)) * NF4 + lane;
  const f4* rp = base + (size_t)row0 * NF4 + lane;

  f4 q1f[C], q2f[C], x[2][C];
  #pragma unroll
  for (int i = 0; i < C; ++i) q1f[i] = q1p[i * 64];
  #pragma unroll
  for (int i = 0; i < C; ++i) q2f[i] = q2p[i * 64];
  #pragma unroll
  for (int i = 0; i < C; ++i) x[0][i] = __builtin_nontemporal_load(rp + i * 64);

  #pragma unroll
  for (int r = 0; r < R; ++r) {
    // Prefetch next row before touching current row's data (stays in flight
    // through this row's FMAs + shuffle chain; vmcnt wait lands next iter).
    if (r + 1 < R) {
      const f4* np = rp + (size_t)(r + 1) * NF4;
      #pragma unroll
      for (int i = 0; i < C; ++i)
        x[(r + 1) & 1][i] = __builtin_nontemporal_load(np + i * 64);
    }
    float s1 = 0.f, s2 = 0.f, sn = 0.f;
    #pragma unroll
    for (int i = 0; i < C; ++i) {
      f4 v = x[r & 1][i];
      s1 += v[0] * q1f[i][0] + v[1] * q1f[i][1] + v[2] * q1f[i][2] + v[3] * q1f[i][3];
      s2 += v[0] * q2f[i][0] + v[1] * q2f[i][1] + v[2] * q2f[i][2] + v[3] * q2f[i][3];
      sn += v[0] * v[0] + v[1] * v[1] + v[2] * v[2] + v[3] * v[3];
    }
    #pragma unroll
    for (int off = 32; off >= 1; off >>= 1) {
      s1 += __shfl_xor(s1, off, 64);
      s2 += __shfl_xor(s2, off, 64);
      sn += __shfl_xor(sn, off, 64);
    }
    if (lane == 0) {
      d1[row0 + r] = s1;
      d2[row0 + r] = s2;
      n2[row0 + r] = sn;
    }
  }
}

// Generic fallback (runtime H): one wave per row.
__global__ __launch_bounds__(256) void row_stats_kernel(
    const float* __restrict__ seq, const int* __restrict__ idxs,
    float* __restrict__ d1, float* __restrict__ d2, float* __restrict__ n2,
    int B, int S, int H) {
  int gtid = blockIdx.x * blockDim.x + threadIdx.x;
  int row = gtid >> 6;
  int lane = threadIdx.x & 63;
  int nrows = B * S;
  if (row >= nrows) return;

  int b = row / S;
  int sep0 = idxs[b * 2 + 0];

  const float* rowp = seq + (size_t)row * H;
  const float* q1p = seq + ((size_t)b * S + 1) * H;
  const float* q2p = seq + ((size_t)b * S + (sep0 - 1)) * H;

  float s1 = 0.f, s2 = 0.f, sn = 0.f;
  for (int h = lane * 4; h < H; h += 64 * 4) {
    float4 x = *reinterpret_cast<const float4*>(rowp + h);
    float4 a = *reinterpret_cast<const float4*>(q1p + h);
    float4 c = *reinterpret_cast<const float4*>(q2p + h);
    s1 += x.x * a.x + x.y * a.y + x.z * a.z + x.w * a.w;
    s2 += x.x * c.x + x.y * c.y + x.z * c.z + x.w * c.w;
    sn += x.x * x.x + x.y * x.y + x.z * x.z + x.w * x.w;
  }
  #pragma unroll
  for (int off = 32; off >= 1; off >>= 1) {
    s1 += __shfl_xor(s1, off, 64);
    s2 += __shfl_xor(s2, off, 64);
    sn += __shfl_xor(sn, off, 64);
  }
  if (lane == 0) {
    d1[row] = s1;
    d2[row] = s2;
    n2[row] = sn;
  }
}

// ---------------------------------------------------------------------------
// Kernel B (L=32 compile-time): one thread per (b,s), full unroll, rsqrt.
// First-occurrence argmax via strict '>' (matches jnp.argmax). Unchanged
// from the passing round-3 version.
// ---------------------------------------------------------------------------
template <int L>
__global__ __launch_bounds__(64) void window_max_fast(
    const float* __restrict__ d1, const float* __restrict__ d2,
    const float* __restrict__ n2, const int* __restrict__ idxs,
    float* __restrict__ out, int S, int nrows) {
  int t = blockIdx.x * 64 + threadIdx.x;
  if (t >= nrows) return;
  int b = t / S;
  int s = t - b * S;

  int sep0 = idxs[b * 2 + 0];
  int sep1 = idxs[b * 2 + 1];

  size_t bS = (size_t)b * S;
  float qn2 = n2[bS + 1] + n2[bS + (sep0 - 1)];
  float my_d1 = d1[t];
  float my_n2 = n2[t];

  const float* d2b = d2 + bS;
  const float* n2b = n2 + bS;

  float best = NEG_INF_F;
  int best_l = 0;
  #pragma unroll
  for (int l = 0; l < L; ++l) {
    int j = min(s + l, S - 1);
    float w2 = n2b[j];
    float v2 = d2b[j];
    float prod = (my_n2 + w2) * qn2;
    float sim = (my_d1 + v2) * __frsqrt_rn(fmaxf(prod, EPS_F * EPS_F));
    sim = (s + l < sep1) ? sim : NEG_INF_F;
    if (sim > best) { best = sim; best_l = l; }
  }

  bool valid_i = (s > sep0) && (s < sep1);
  out[t] = valid_i ? best : NEG_INF_F;
  out[nrows + t] = valid_i ? (float)(s + best_l) : -1.0f;
}

// Generic fallback (runtime L), precise math.
__global__ __launch_bounds__(256) void window_max_kernel(
    const float* __restrict__ d1, const float* __restrict__ d2,
    const float* __restrict__ n2, const int* __restrict__ idxs,
    const int* __restrict__ pL,
    float* __restrict__ out, int B, int S) {
  int t = blockIdx.x * blockDim.x + threadIdx.x;
  int nrows = B * S;
  if (t >= nrows) return;
  int b = t / S;
  int s = t - b * S;

  int sep0 = idxs[b * 2 + 0];
  int sep1 = idxs[b * 2 + 1];
  int L = pL[0];

  float qn2 = n2[(size_t)b * S + 1] + n2[(size_t)b * S + (sep0 - 1)];
  float my_d1 = d1[t];
  float my_n2 = n2[t];

  float best = NEG_INF_F;
  int best_l = 0;
  const float* d2b = d2 + (size_t)b * S;
  const float* n2b = n2 + (size_t)b * S;
  for (int l = 0; l < L; ++l) {
    float sim;
    if (s + l < sep1) {
      int j = min(s + l, S - 1);
      float denom = fmaxf(sqrtf((my_n2 + n2b[j]) * qn2), EPS_F);
      sim = (my_d1 + d2b[j]) / denom;
    } else {
      sim = NEG_INF_F;
    }
    if (sim > best) { best = sim; best_l = l; }
  }

  bool valid_i = (s > sep0) && (s < sep1);
  out[t] = valid_i ? best : NEG_INF_F;
  out[nrows + t] = valid_i ? (float)(s + best_l) : -1.0f;
}

extern "C" void kernel_launch(void* const* d_in, const int* in_sizes, int n_in,
                              void* d_out, int out_size, void* d_ws, size_t ws_size,
                              hipStream_t stream) {
  const float* seq = (const float*)d_in[0];
  const int* idxs = (const int*)d_in[1];
  const int* pL = (const int*)d_in[2];

  int B = in_sizes[1] / 2;
  int S = out_size / (2 * B);
  int H = (int)((long long)in_sizes[0] / ((long long)B * S));
  int nrows = B * S;

  float* d1 = (float*)d_ws;
  float* d2 = d1 + nrows;
  float* n2 = d2 + nrows;

  if (H == 1024 && (S % 4) == 0 && (nrows % 16) == 0) {
    // 4 rows per wave (pipelined), 4 waves per block -> 16 rows per block.
    int gridA = nrows / 16;
    row_stats_pipe<1024><<<gridA, 256, 0, stream>>>(seq, idxs, d1, d2, n2, S,
                                                    nrows);
  } else {
    int gridA = (nrows + 3) / 4;
    row_stats_kernel<<<gridA, 256, 0, stream>>>(seq, idxs, d1, d2, n2, B, S, H);
  }

  int gridB = (nrows + 63) / 64;
  window_max_fast<32><<<gridB, 64, 0, stream>>>(d1, d2, n2, idxs,
                                                (float*)d_out, S, nrows);
  (void)pL;
}